// Round 1
// baseline (88.535 us; speedup 1.0000x reference)
//
#include <hip/hip_runtime.h>

#define C_CURV   0.01f
#define SQRT_C   0.1f
#define EPS_W    1e-6f
#define MIN_NORM 1e-10f
#define BALL_EPS 1e-5f

__device__ __forceinline__ float group16_sum(float v) {
    v += __shfl_xor(v, 1, 16);
    v += __shfl_xor(v, 2, 16);
    v += __shfl_xor(v, 4, 16);
    v += __shfl_xor(v, 8, 16);
    return v;
}

// Phase A: per node, 16 lanes/node. h_tan = log0(h_hyper); loop_hyp = exp0(h_tan @ loop_weight)
__global__ __launch_bounds__(256) void fhnn_node_pre(
        const float* __restrict__ h_hyper,
        const float* __restrict__ loop_weight,
        float* __restrict__ h_tan,
        float* __restrict__ loop_hyp,
        int N) {
    __shared__ float Wl[256];
    Wl[threadIdx.x] = loop_weight[threadIdx.x];
    __syncthreads();

    int gid = blockIdx.x * blockDim.x + threadIdx.x;
    int t = gid >> 4, j = gid & 15;
    if (t >= N) return;

    float xj = h_hyper[gid];                 // gid == t*16 + j
    float sq = group16_sum(xj * xj);
    float n  = sqrtf(fmaxf(sq, MIN_NORM));
    float scn = SQRT_C * n;
    float z = fminf(fmaxf(scn, -1.0f + BALL_EPS), 1.0f - BALL_EPS);
    float at = 0.5f * logf((1.0f + z) / (1.0f - z));   // arctanh(z)
    float htj = at * xj / scn;
    h_tan[gid] = htj;

    // lt_j = sum_i ht_i * Wl[i][j]
    float acc = 0.0f;
    #pragma unroll
    for (int i = 0; i < 16; ++i) {
        float hi = __shfl(htj, i, 16);
        acc = fmaf(hi, Wl[i * 16 + j], acc);
    }
    float sq2 = group16_sum(acc * acc);
    float n2  = sqrtf(fmaxf(sq2, MIN_NORM));
    float scn2 = SQRT_C * n2;
    float f = tanhf(scn2) / scn2;
    loop_hyp[gid] = f * acc;
}

// Phase B: per edge, 16 lanes/edge. msg = exp0(h_tan[src] @ W[etype] + rel_emb[etype]);
// accumulate S_num += en*lam*msg, S_den += en*lam, Ns += en at dst.
__global__ __launch_bounds__(256) void fhnn_edge(
        const float* __restrict__ h_tan,
        const float* __restrict__ node_norm,
        const float* __restrict__ rel_weight,
        const float* __restrict__ rel_emb,
        const int*   __restrict__ src,
        const int*   __restrict__ dst,
        const int*   __restrict__ etype,
        float* __restrict__ S_num,
        float* __restrict__ S_den,
        float* __restrict__ Ns,
        int E) {
    int gid = blockIdx.x * blockDim.x + threadIdx.x;
    int e = gid >> 4, j = gid & 15;
    if (e >= E) return;

    int s = src[e], t = dst[e], r = etype[e];
    float hj = h_tan[s * 16 + j];
    const float* W = rel_weight + (size_t)r * 256;

    float acc = 0.0f;
    #pragma unroll
    for (int i = 0; i < 16; ++i) {
        float hi = __shfl(hj, i, 16);
        acc = fmaf(hi, W[i * 16 + j], acc);   // coalesced: lanes j=0..15 read a row of 16 floats
    }
    float v = acc + rel_emb[r * 16 + j];

    float sq = group16_sum(v * v);            // raw sum(v^2)
    float n  = sqrtf(fmaxf(sq, MIN_NORM));
    float scn = SQRT_C * n;
    float f = tanhf(scn) / scn;
    float msg = f * v;
    float m2 = f * f * sq;                    // sum(msg^2)
    float lam = 2.0f / (1.0f - C_CURV * m2 + EPS_W);

    float en = node_norm[t];
    float wl = en * lam;

    atomicAdd(&S_num[t * 16 + j], wl * msg);
    if (j == 0) {
        atomicAdd(&S_den[t], wl);
        atomicAdd(&Ns[t], en);
    }
}

// Phase C: per node. h_agg = project(S_num / (S_den + EPS*(ns+EPS))); out = mobius_add(h_agg, loop_hyp)
__global__ __launch_bounds__(256) void fhnn_node_post(
        const float* __restrict__ S_num,
        const float* __restrict__ S_den,
        const float* __restrict__ Ns,
        const float* __restrict__ loop_hyp,
        float* __restrict__ out,
        int N) {
    int gid = blockIdx.x * blockDim.x + threadIdx.x;
    int t = gid >> 4, j = gid & 15;
    if (t >= N) return;

    float ns_t = Ns[t];
    float den = S_den[t] + EPS_W * (ns_t + EPS_W);
    float xj = S_num[gid] / den;

    // project_to_ball
    float x2 = group16_sum(xj * xj);
    float n  = sqrtf(fmaxf(x2, MIN_NORM));
    const float maxn = (1.0f - BALL_EPS) / SQRT_C;
    xj *= (n > maxn) ? (maxn / n) : 1.0f;

    float x2p = group16_sum(xj * xj);
    float yj  = loop_hyp[gid];
    float y2  = group16_sum(yj * yj);
    float xy  = group16_sum(xj * yj);

    float a = 1.0f + 2.0f * C_CURV * xy + C_CURV * y2;
    float b = 1.0f - C_CURV * x2p;
    float num = a * xj + b * yj;
    float d2  = 1.0f + 2.0f * C_CURV * xy + C_CURV * C_CURV * x2p * y2;
    out[gid] = num / fmaxf(d2, MIN_NORM);
}

extern "C" void kernel_launch(void* const* d_in, const int* in_sizes, int n_in,
                              void* d_out, int out_size, void* d_ws, size_t ws_size,
                              hipStream_t stream) {
    const float* h_hyper     = (const float*)d_in[0];
    const float* node_norm   = (const float*)d_in[1];
    const float* rel_weight  = (const float*)d_in[2];
    const float* loop_weight = (const float*)d_in[3];
    const float* rel_emb     = (const float*)d_in[4];
    const int*   src         = (const int*)d_in[5];
    const int*   dst         = (const int*)d_in[6];
    const int*   etype       = (const int*)d_in[7];

    const int N = in_sizes[1];   // node_norm is [N,1]
    const int E = in_sizes[5];

    char* ws = (char*)d_ws;
    size_t offs = 0;
    auto alloc = [&](size_t bytes) -> void* {
        void* p = ws + offs;
        offs += (bytes + 255) & ~(size_t)255;
        return p;
    };
    float* h_tan    = (float*)alloc((size_t)N * 16 * 4);
    float* loop_hyp = (float*)alloc((size_t)N * 16 * 4);
    float* S_num    = (float*)alloc((size_t)N * 16 * 4);
    float* S_den    = (float*)alloc((size_t)N * 4);
    float* Ns       = (float*)alloc((size_t)N * 4);

    // zero the atomic accumulators every call (contiguous range: S_num..Ns end)
    size_t zero_bytes = (size_t)((char*)Ns - (char*)S_num) + ((size_t)N * 4 + 255 & ~(size_t)255);
    hipMemsetAsync(S_num, 0, zero_bytes, stream);

    const int threads = 256;
    int blocksN = (N * 16 + threads - 1) / threads;
    int blocksE = (int)(((long long)E * 16 + threads - 1) / threads);

    fhnn_node_pre<<<blocksN, threads, 0, stream>>>(h_hyper, loop_weight, h_tan, loop_hyp, N);
    fhnn_edge<<<blocksE, threads, 0, stream>>>(h_tan, node_norm, rel_weight, rel_emb,
                                               src, dst, etype, S_num, S_den, Ns, E);
    fhnn_node_post<<<blocksN, threads, 0, stream>>>(S_num, S_den, Ns, loop_hyp, (float*)d_out, N);
}